// Round 15
// baseline (196.616 us; speedup 1.0000x reference)
//
#include <hip/hip_runtime.h>
#include <hip/hip_bf16.h>

#define NH 16
#define S 1024
#define DH 64
#define DM 1024
#define MTOK 4096

typedef __attribute__((ext_vector_type(8))) short bf16x8;
typedef __attribute__((ext_vector_type(4))) float f32x4;
typedef __attribute__((ext_vector_type(16))) float f32x16;
typedef __attribute__((ext_vector_type(8))) unsigned short u16x8;
typedef __attribute__((ext_vector_type(4))) unsigned short u16x4;

__device__ inline unsigned short f2bf(float x) {
  __hip_bfloat16 h = __float2bfloat16(x);
  return __builtin_bit_cast(unsigned short, h);
}

__device__ inline unsigned cvt_pk_bf16(float lo, float hi_) {
  unsigned r;
  asm("v_cvt_pk_bf16_f32 %0, %1, %2" : "=v"(r) : "v"(lo), "v"(hi_));
  return r;
}

__device__ inline void gload16(const void* g, void* lds) {
  __builtin_amdgcn_global_load_lds((const __attribute__((address_space(1))) void*)g,
                                   (__attribute__((address_space(3))) void*)lds, 16, 0, 0);
}

// ---------------------------------------------------------------------------
// fp32 -> bf16 for all 7 tensors.  2048 blocks, grid-stride x4.
// R15: NONTEMPORAL loads -- inputs are read exactly once; don't evict the
// L2/L3 lines proj is about to need.
// ---------------------------------------------------------------------------
__global__ __launch_bounds__(256) void cvt_all(
    const float* __restrict__ q, const float* __restrict__ k, const float* __restrict__ v,
    const float* __restrict__ wq, const float* __restrict__ wk,
    const float* __restrict__ wv, const float* __restrict__ wo,
    unsigned short* __restrict__ xq, unsigned short* __restrict__ xk,
    unsigned short* __restrict__ xv, unsigned short* __restrict__ wqb,
    unsigned short* __restrict__ wkb, unsigned short* __restrict__ wvb,
    unsigned short* __restrict__ wob) {
  for (int bid = blockIdx.x; bid < 8192; bid += 2048) {
    const float* src;
    unsigned short* dst;
    int lb;
    if (bid < 6144) {
      const int r = bid >> 11;
      lb = bid & 2047;
      src = (r == 0) ? q : ((r == 1) ? k : v);
      dst = (r == 0) ? xq : ((r == 1) ? xk : xv);
    } else {
      const int r = (bid - 6144) >> 9;
      lb = (bid - 6144) & 511;
      src = (r == 0) ? wq : ((r == 1) ? wk : ((r == 2) ? wv : wo));
      dst = (r == 0) ? wqb : ((r == 1) ? wkb : ((r == 2) ? wvb : wob));
    }
    const int i = lb * 256 + threadIdx.x;
    const f32x4* s4 = (const f32x4*)(src + (size_t)i * 8);
    f32x4 v0 = __builtin_nontemporal_load(s4);
    f32x4 v1 = __builtin_nontemporal_load(s4 + 1);
    u16x8 o;
    o[0] = f2bf(v0[0]); o[1] = f2bf(v0[1]); o[2] = f2bf(v0[2]); o[3] = f2bf(v0[3]);
    o[4] = f2bf(v1[0]); o[5] = f2bf(v1[1]); o[6] = f2bf(v1[2]); o[7] = f2bf(v1[3]);
    *(u16x8*)(dst + (size_t)i * 8) = o;
  }
}

// ---------------------------------------------------------------------------
// BK=64 m97-style GEMM core.  BM x 128 tile, 4 waves (2x2), gload_lds w16.
// SWAP=0: acc[m][n] = mfma(a[m], b[n], .)  -> D: col=cl->n, reg->m
// SWAP=1: acc[m][n] = mfma(b[n], a[m], .)  -> D: col=cl->m, reg->n
// ---------------------------------------------------------------------------
template <int BM, int SWAP>
__device__ inline void gemm_core_bk64(const unsigned short* __restrict__ X,
                                      const unsigned short* __restrict__ W,
                                      unsigned short* As, unsigned short* Bs,
                                      int m0, int n0, f32x4 (&acc)[BM / 32][4]) {
  constexpr int ACH = BM / 32;
  const int t = threadIdx.x, l = t & 63, w = t >> 6;
  const int wr = w >> 1, wc = w & 1, cl = l & 15, kg = l >> 4;
  const int lr = l >> 3;
  const int lc = (l & 7) * 8;

  const unsigned short* gaB = X + (size_t)(m0 + lr) * DM + lc;
  const unsigned short* gbB = W + (size_t)(n0 + lr) * DM + lc;

  for (int kt = 0; kt < DM; kt += 64) {
    __syncthreads();
#pragma unroll
    for (int c = 0; c < ACH; ++c) {
      const int ch = w * ACH + c;
      gload16(gaB + (size_t)(ch * 8) * DM + kt, (char*)As + ch * 1024);
    }
#pragma unroll
    for (int c = 0; c < 4; ++c) {
      const int ch = w * 4 + c;
      gload16(gbB + (size_t)(ch * 8) * DM + kt, (char*)Bs + ch * 1024);
    }
    __syncthreads();
#pragma unroll
    for (int kk = 0; kk < 2; ++kk) {
      bf16x8 a[ACH], b[4];
#pragma unroll
      for (int m = 0; m < ACH; ++m)
        a[m] = *(const bf16x8*)&As[(wr * (BM / 2) + m * 16 + cl) * 64 + kk * 32 + kg * 8];
#pragma unroll
      for (int n = 0; n < 4; ++n)
        b[n] = *(const bf16x8*)&Bs[(wc * 64 + n * 16 + cl) * 64 + kk * 32 + kg * 8];
#pragma unroll
      for (int m = 0; m < ACH; ++m)
#pragma unroll
        for (int n = 0; n < 4; ++n) {
          if (SWAP)
            acc[m][n] = __builtin_amdgcn_mfma_f32_16x16x32_bf16(b[n], a[m], acc[m][n], 0, 0, 0);
          else
            acc[m][n] = __builtin_amdgcn_mfma_f32_16x16x32_bf16(a[m], b[n], acc[m][n], 0, 0, 0);
        }
    }
  }
}

// Fused Q/K/V projections, 128x128 tiles, BK=64.  Grid: 1-D 768, XCD-chunked.
__global__ __launch_bounds__(256) void proj_gemm(
    const unsigned short* __restrict__ X0, const unsigned short* __restrict__ X1,
    const unsigned short* __restrict__ X2, const unsigned short* __restrict__ W0,
    const unsigned short* __restrict__ W1, const unsigned short* __restrict__ W2,
    const float* __restrict__ b0, const float* __restrict__ b1, const float* __restrict__ b2,
    unsigned short* __restrict__ Y0, unsigned short* __restrict__ Y1,
    unsigned short* __restrict__ Y2) {
  __shared__ unsigned short As[128 * 64];
  __shared__ unsigned short Bs[128 * 64];
  const int bid = blockIdx.x;
  const int wg = (bid & 7) * 96 + (bid >> 3);   // bijective: 768 = 8 * 96
  const int z = wg >> 8;
  const int rem = wg & 255;
  const int m0 = (rem >> 3) * 128, n0 = (rem & 7) * 128;

  const unsigned short* X = (z == 0) ? X0 : ((z == 1) ? X1 : X2);
  const unsigned short* W = (z == 0) ? W0 : ((z == 1) ? W1 : W2);
  const float* bias = (z == 0) ? b0 : ((z == 1) ? b1 : b2);

  const int l = threadIdx.x & 63, w = threadIdx.x >> 6;
  const int wr = w >> 1, wc = w & 1, cl = l & 15, kg = l >> 4;

  f32x4 acc[4][4] = {};
  if (z == 2) {
    gemm_core_bk64<128, 0>(X, W, As, Bs, m0, n0, acc);
#pragma unroll
    for (int i = 0; i < 4; ++i) {
#pragma unroll
      for (int j = 0; j < 4; ++j) {
        const int gn = n0 + wc * 64 + j * 16 + cl;
        const float bv = bias[gn];
        const int h_ = gn >> 6, d_ = gn & 63;
        const int gm0 = m0 + wr * 64 + i * 16 + kg * 4;
        const int b_ = gm0 >> 10, s0 = gm0 & 1023;
        u16x4 vv;
#pragma unroll
        for (int r = 0; r < 4; ++r) vv[r] = f2bf(acc[i][j][r] + bv);
        *(u16x4*)&Y2[((size_t)(b_ * NH + h_) * DH + d_) * S + s0] = vv;
      }
    }
  } else {
    gemm_core_bk64<128, 1>(X, W, As, Bs, m0, n0, acc);
    unsigned short* Y = (z == 0) ? Y0 : Y1;
    const bool scale = (z == 1);
#pragma unroll
    for (int i = 0; i < 4; ++i) {
      const int gm = m0 + wr * 64 + i * 16 + cl;
      const int b_ = gm >> 10, s_ = gm & 1023;
#pragma unroll
      for (int j = 0; j < 4; ++j) {
        const int gn0 = n0 + wc * 64 + j * 16 + kg * 4;
        const int h_ = gn0 >> 6, d0 = gn0 & 63;
        const f32x4 bv = *(const f32x4*)(bias + gn0);
        u16x4 vv;
#pragma unroll
        for (int r = 0; r < 4; ++r) {
          float val = acc[i][j][r] + bv[r];
          if (scale) val *= 0.125f;
          vv[r] = f2bf(val);
        }
        *(u16x4*)&Y[((size_t)(b_ * NH + h_) * S + s_) * DH + d0] = vv;
      }
    }
  }
}

// Final GEMM: out0 = OutH @ Wo^T + bo (fp32), 64x128 tiles, BK=64, SWAPPED.
// R15: NONTEMPORAL output stores (write-only stream, never re-read).
__global__ __launch_bounds__(256) void out_gemm(const unsigned short* __restrict__ X,
                                                const unsigned short* __restrict__ W,
                                                const float* __restrict__ bias,
                                                float* __restrict__ Y) {
  __shared__ unsigned short As[64 * 64];
  __shared__ unsigned short Bs[128 * 64];
  const int bid = blockIdx.x;
  const int wg = (bid & 7) * 64 + (bid >> 3);   // 512 = 8 * 64
  const int m0 = (wg >> 3) * 64, n0 = (wg & 7) * 128;

  f32x4 acc[2][4] = {};
  gemm_core_bk64<64, 1>(X, W, As, Bs, m0, n0, acc);

  const int l = threadIdx.x & 63, w = threadIdx.x >> 6;
  const int wr = w >> 1, wc = w & 1, cl = l & 15, kg = l >> 4;
#pragma unroll
  for (int i = 0; i < 2; ++i) {
    const int gm = m0 + wr * 32 + i * 16 + cl;
#pragma unroll
    for (int j = 0; j < 4; ++j) {
      const int gn0 = n0 + wc * 64 + j * 16 + kg * 4;
      const f32x4 bv = *(const f32x4*)(bias + gn0);
      f32x4 st;
#pragma unroll
      for (int r = 0; r < 4; ++r) st[r] = acc[i][j][r] + bv[r];
      __builtin_nontemporal_store(st, (f32x4*)&Y[(size_t)gm * DM + gn0]);
    }
  }
}

// ---------------------------------------------------------------------------
// kv-split attention (R14-exact, best measured): LDS-coalesced prob staging
// + NONTEMPORAL streaming stores (268MB bypasses L2 -> K/V stay resident).
// Block = 8 waves (512 thr), 32 q-rows; wave w owns kv [w*128, w*128+128).
// Grid: 1-D 2048, XCD-chunked by head.
// ---------------------------------------------------------------------------
__global__ __launch_bounds__(512, 4) void attn_mfma(const unsigned short* __restrict__ Qh,
                                                    const unsigned short* __restrict__ Kh,
                                                    const unsigned short* __restrict__ Vt,
                                                    float* __restrict__ attn,
                                                    unsigned short* __restrict__ OutH) {
  __shared__ float sums[8][32];
  __shared__ float invs[32];
  __shared__ float Buf[8 * 32 * 66];            // 67.6 KB, dual-use
  unsigned short* Ppk = (unsigned short*)Buf;   // [32][1028] halfwords (65.8 KB)
  float (*Olds)[32][66] = (float (*)[32][66])Buf;

  const int t = threadIdx.x, l = t & 63, w = t >> 6;
  const int lq = l & 31, hi = l >> 5;
  const int bid = blockIdx.x;
  const int wg = (bid & 7) * 256 + (bid >> 3);  // bijective: 2048 = 8 * 256
  const int bh = wg >> 5;
  const int q0 = (wg & 31) * 32;

  const unsigned short* kb = Kh + (size_t)bh * S * DH;
  const unsigned short* vb = Vt + (size_t)bh * DH * S;

  unsigned e_pk[4][8];
  float sum = 0.f;

  // ---- pass A: QK^T + exp + partial row sums; retain packed exp(S) ----
  {
    const unsigned short* qp = Qh + ((size_t)bh * S + q0 + lq) * DH + hi * 8;
    bf16x8 qf0 = *(const bf16x8*)(qp);
    bf16x8 qf1 = *(const bf16x8*)(qp + 16);
    bf16x8 qf2 = *(const bf16x8*)(qp + 32);
    bf16x8 qf3 = *(const bf16x8*)(qp + 48);
#pragma unroll
    for (int kt = 0; kt < 4; ++kt) {
      const unsigned short* kp = kb + (size_t)(w * 128 + kt * 32 + lq) * DH + hi * 8;
      f32x16 acc = {};
      __builtin_amdgcn_s_setprio(1);
      acc = __builtin_amdgcn_mfma_f32_32x32x16_bf16(*(const bf16x8*)(kp),      qf0, acc, 0, 0, 0);
      acc = __builtin_amdgcn_mfma_f32_32x32x16_bf16(*(const bf16x8*)(kp + 16), qf1, acc, 0, 0, 0);
      acc = __builtin_amdgcn_mfma_f32_32x32x16_bf16(*(const bf16x8*)(kp + 32), qf2, acc, 0, 0, 0);
      acc = __builtin_amdgcn_mfma_f32_32x32x16_bf16(*(const bf16x8*)(kp + 48), qf3, acc, 0, 0, 0);
      __builtin_amdgcn_s_setprio(0);
      float e[16];
#pragma unroll
      for (int r = 0; r < 16; ++r) e[r] = __expf(acc[r]);
#pragma unroll
      for (int r = 0; r < 16; ++r) sum += e[r];
#pragma unroll
      for (int j = 0; j < 8; ++j) e_pk[kt][j] = cvt_pk_bf16(e[2 * j], e[2 * j + 1]);
    }
  }
  sum += __shfl_xor(sum, 32);
  if (l < 32) sums[w][lq] = sum;
  __syncthreads();
  float tot = 0.f;
#pragma unroll
  for (int p = 0; p < 8; ++p) tot += sums[p][lq];
  const float inv = 1.0f / tot;
  if (t < 32) invs[lq] = inv;   // wave 0, lanes 0..31

  // ---- pass B: P -> LDS (packed bf16) + PV on unnormalized e ----
  f32x16 o0 = {}, o1 = {};

#pragma unroll
  for (int kt = 0; kt < 4; ++kt) {
    // ds_write_b64: words (j, j+1) are kv-contiguous quads
#pragma unroll
    for (int j = 0; j < 8; j += 2) {
      const unsigned long long pv =
          ((unsigned long long)e_pk[kt][j + 1] << 32) | (unsigned long long)e_pk[kt][j];
      const int kvb = w * 128 + kt * 32 + (j >> 1) * 8 + 4 * hi;
      *(unsigned long long*)&Ppk[lq * 1028 + kvb] = pv;
    }

    // PV B-frags directly from the packed words (kv slices 0..15 / 16..31)
    const unsigned wds0 = e_pk[kt][0], wds1 = e_pk[kt][1];
    const unsigned wds2 = e_pk[kt][2], wds3 = e_pk[kt][3];
    const unsigned wds4 = e_pk[kt][4], wds5 = e_pk[kt][5];
    const unsigned wds6 = e_pk[kt][6], wds7 = e_pk[kt][7];
    const unsigned x0 = __shfl_xor((int)wds0, 32), x1 = __shfl_xor((int)wds1, 32);
    const unsigned x2 = __shfl_xor((int)wds2, 32), x3 = __shfl_xor((int)wds3, 32);
    const unsigned x4 = __shfl_xor((int)wds4, 32), x5 = __shfl_xor((int)wds5, 32);
    const unsigned x6 = __shfl_xor((int)wds6, 32), x7 = __shfl_xor((int)wds7, 32);
    union UU { unsigned u[4]; bf16x8 v; } f0, f1;
    f0.u[0] = hi ? x2 : wds0;  f0.u[1] = hi ? x3 : wds1;
    f0.u[2] = hi ? wds2 : x0;  f0.u[3] = hi ? wds3 : x1;
    f1.u[0] = hi ? x6 : wds4;  f1.u[1] = hi ? x7 : wds5;
    f1.u[2] = hi ? wds6 : x4;  f1.u[3] = hi ? wds7 : x5;

    {
      const unsigned short* vp = vb + (size_t)(lq)*S + w * 128 + kt * 32 + hi * 8;
      bf16x8 v0 = *(const bf16x8*)vp;
      bf16x8 v1 = *(const bf16x8*)(vp + 16);
      const unsigned short* vp1 = vb + (size_t)(32 + lq) * S + w * 128 + kt * 32 + hi * 8;
      bf16x8 v2 = *(const bf16x8*)vp1;
      bf16x8 v3 = *(const bf16x8*)(vp1 + 16);
      __builtin_amdgcn_s_setprio(1);
      o0 = __builtin_amdgcn_mfma_f32_32x32x16_bf16(v0, f0.v, o0, 0, 0, 0);
      o0 = __builtin_amdgcn_mfma_f32_32x32x16_bf16(v1, f1.v, o0, 0, 0, 0);
      o1 = __builtin_amdgcn_mfma_f32_32x32x16_bf16(v2, f0.v, o1, 0, 0, 0);
      o1 = __builtin_amdgcn_mfma_f32_32x32x16_bf16(v3, f1.v, o1, 0, 0, 0);
      __builtin_amdgcn_s_setprio(0);
    }
  }
  __syncthreads();  // all waves' P tiles in LDS

  // ---- streaming probs: coalesced 1KB-per-wave-store, NONTEMPORAL ----
  {
    float* ab = attn + ((size_t)bh << 20) + ((size_t)q0 << 10);
#pragma unroll
    for (int i = 0; i < 16; ++i) {
      const int f = t + i * 512;            // quad index 0..8191
      const int q = f >> 8, c4 = (f & 255) * 4;
      const unsigned long long pk = *(const unsigned long long*)&Ppk[q * 1028 + c4];
      const unsigned lo = (unsigned)pk, hi2 = (unsigned)(pk >> 32);
      const float iv = invs[q];
      f32x4 pv;
      pv[0] = __builtin_bit_cast(float, lo << 16) * iv;
      pv[1] = __builtin_bit_cast(float, lo & 0xffff0000u) * iv;
      pv[2] = __builtin_bit_cast(float, hi2 << 16) * iv;
      pv[3] = __builtin_bit_cast(float, hi2 & 0xffff0000u) * iv;
      __builtin_nontemporal_store(pv, (f32x4*)(ab + (size_t)q * 1024 + c4));
    }
  }
  __syncthreads();  // P region dead; Olds may overwrite

  // ---- apply row normalization once, combine partial O via LDS (f32x4) ----
#pragma unroll
  for (int r = 0; r < 16; ++r) { o0[r] *= inv; o1[r] *= inv; }
  {
    float* orow = &Olds[w][lq][0];
#pragma unroll
    for (int g = 0; g < 4; ++g) {
      f32x4 a = {o0[4 * g], o0[4 * g + 1], o0[4 * g + 2], o0[4 * g + 3]};
      *(f32x4*)(orow + 8 * g + 4 * hi) = a;           // d = 8g+4hi .. +3
      f32x4 b2 = {o1[4 * g], o1[4 * g + 1], o1[4 * g + 2], o1[4 * g + 3]};
      *(f32x4*)(orow + 32 + 8 * g + 4 * hi) = b2;     // d = 32+8g+4hi .. +3
    }
  }
  __syncthreads();

  {
    const int qq = t >> 4, d0 = (t & 15) * 4;   // all 512 threads
    const int b_ = bh >> 4, h_ = bh & 15;
    f32x4 s = {0.f, 0.f, 0.f, 0.f};
#pragma unroll
    for (int p = 0; p < 8; ++p) {
      const f32x4 v = *(const f32x4*)&Olds[p][qq][d0];
      s[0] += v[0]; s[1] += v[1]; s[2] += v[2]; s[3] += v[3];
    }
    u16x4 ov;
#pragma unroll
    for (int i = 0; i < 4; ++i) ov[i] = f2bf(s[i]);
    *(u16x4*)&OutH[((size_t)(b_ * S + q0 + qq)) * DM + h_ * DH + d0] = ov;
  }
}

// ---------------------------------------------------------------------------
extern "C" void kernel_launch(void* const* d_in, const int* in_sizes, int n_in,
                              void* d_out, int out_size, void* d_ws, size_t ws_size,
                              hipStream_t stream) {
  const float* query = (const float*)d_in[0];
  const float* key_  = (const float*)d_in[1];
  const float* value = (const float*)d_in[2];
  const float* Wq = (const float*)d_in[3];
  const float* bq = (const float*)d_in[4];
  const float* Wk = (const float*)d_in[5];
  const float* bk = (const float*)d_in[6];
  const float* Wv = (const float*)d_in[7];
  const float* bv = (const float*)d_in[8];
  const float* Wo = (const float*)d_in[9];
  const float* bo = (const float*)d_in[10];

  float* out0 = (float*)d_out;
  float* attn = out0 + (size_t)MTOK * DM;

  const size_t M1 = 1u << 20;
  unsigned short* wsu = (unsigned short*)d_ws;
  unsigned short* Xq  = wsu;
  unsigned short* Xk  = wsu + 4 * M1;
  unsigned short* Xv  = wsu + 8 * M1;
  unsigned short* Wqb = wsu + 12 * M1;
  unsigned short* Wkb = wsu + 13 * M1;
  unsigned short* Wvb = wsu + 14 * M1;
  unsigned short* Wob = wsu + 15 * M1;
  unsigned short* Qh  = wsu + 16 * M1;
  unsigned short* Kh  = wsu + 20 * M1;
  unsigned short* Vt  = wsu + 24 * M1;
  unsigned short* OutH= wsu + 28 * M1;

  dim3 tB(256);
  hipLaunchKernelGGL(cvt_all, dim3(2048), tB, 0, stream, query, key_, value, Wq, Wk, Wv, Wo,
                     Xq, Xk, Xv, Wqb, Wkb, Wvb, Wob);

  hipLaunchKernelGGL(proj_gemm, dim3(768), tB, 0, stream,
                     Xq, Xk, Xv, Wqb, Wkb, Wvb, bq, bk, bv, Qh, Kh, Vt);

  hipLaunchKernelGGL(attn_mfma, dim3(2048), dim3(512), 0, stream, Qh, Kh, Vt, attn, OutH);

  hipLaunchKernelGGL(out_gemm, dim3(512), tB, 0, stream, OutH, Wob, bo, out0);
}

// Round 16
// 194.128 us; speedup vs baseline: 1.0128x; 1.0128x over previous
//
#include <hip/hip_runtime.h>
#include <hip/hip_bf16.h>

#define NH 16
#define S 1024
#define DH 64
#define DM 1024
#define MTOK 4096

typedef __attribute__((ext_vector_type(8))) short bf16x8;
typedef __attribute__((ext_vector_type(4))) float f32x4;
typedef __attribute__((ext_vector_type(16))) float f32x16;
typedef __attribute__((ext_vector_type(8))) unsigned short u16x8;
typedef __attribute__((ext_vector_type(4))) unsigned short u16x4;

__device__ inline unsigned short f2bf(float x) {
  __hip_bfloat16 h = __float2bfloat16(x);
  return __builtin_bit_cast(unsigned short, h);
}

__device__ inline unsigned cvt_pk_bf16(float lo, float hi_) {
  unsigned r;
  asm("v_cvt_pk_bf16_f32 %0, %1, %2" : "=v"(r) : "v"(lo), "v"(hi_));
  return r;
}

__device__ inline void gload16(const void* g, void* lds) {
  __builtin_amdgcn_global_load_lds((const __attribute__((address_space(1))) void*)g,
                                   (__attribute__((address_space(3))) void*)lds, 16, 0, 0);
}

// ---------------------------------------------------------------------------
// fp32 -> bf16 for all 7 tensors.  2048 blocks, grid-stride x4.
// ---------------------------------------------------------------------------
__global__ __launch_bounds__(256) void cvt_all(
    const float* __restrict__ q, const float* __restrict__ k, const float* __restrict__ v,
    const float* __restrict__ wq, const float* __restrict__ wk,
    const float* __restrict__ wv, const float* __restrict__ wo,
    unsigned short* __restrict__ xq, unsigned short* __restrict__ xk,
    unsigned short* __restrict__ xv, unsigned short* __restrict__ wqb,
    unsigned short* __restrict__ wkb, unsigned short* __restrict__ wvb,
    unsigned short* __restrict__ wob) {
  for (int bid = blockIdx.x; bid < 8192; bid += 2048) {
    const float* src;
    unsigned short* dst;
    int lb;
    if (bid < 6144) {
      const int r = bid >> 11;
      lb = bid & 2047;
      src = (r == 0) ? q : ((r == 1) ? k : v);
      dst = (r == 0) ? xq : ((r == 1) ? xk : xv);
    } else {
      const int r = (bid - 6144) >> 9;
      lb = (bid - 6144) & 511;
      src = (r == 0) ? wq : ((r == 1) ? wk : ((r == 2) ? wv : wo));
      dst = (r == 0) ? wqb : ((r == 1) ? wkb : ((r == 2) ? wvb : wob));
    }
    const int i = lb * 256 + threadIdx.x;
    const float4* s4 = (const float4*)(src + (size_t)i * 8);
    float4 v0 = s4[0], v1 = s4[1];
    u16x8 o;
    o[0] = f2bf(v0.x); o[1] = f2bf(v0.y); o[2] = f2bf(v0.z); o[3] = f2bf(v0.w);
    o[4] = f2bf(v1.x); o[5] = f2bf(v1.y); o[6] = f2bf(v1.z); o[7] = f2bf(v1.w);
    *(u16x8*)(dst + (size_t)i * 8) = o;
  }
}

// ---------------------------------------------------------------------------
// BK=64 m97-style GEMM core.  BM x 128 tile, 4 waves (2x2), gload_lds w16.
// SWAP=0: acc[m][n] = mfma(a[m], b[n], .)  -> D: col=cl->n, reg->m
// SWAP=1: acc[m][n] = mfma(b[n], a[m], .)  -> D: col=cl->m, reg->n
// ---------------------------------------------------------------------------
template <int BM, int SWAP>
__device__ inline void gemm_core_bk64(const unsigned short* __restrict__ X,
                                      const unsigned short* __restrict__ W,
                                      unsigned short* As, unsigned short* Bs,
                                      int m0, int n0, f32x4 (&acc)[BM / 32][4]) {
  constexpr int ACH = BM / 32;
  const int t = threadIdx.x, l = t & 63, w = t >> 6;
  const int wr = w >> 1, wc = w & 1, cl = l & 15, kg = l >> 4;
  const int lr = l >> 3;
  const int lc = (l & 7) * 8;

  const unsigned short* gaB = X + (size_t)(m0 + lr) * DM + lc;
  const unsigned short* gbB = W + (size_t)(n0 + lr) * DM + lc;

  for (int kt = 0; kt < DM; kt += 64) {
    __syncthreads();
#pragma unroll
    for (int c = 0; c < ACH; ++c) {
      const int ch = w * ACH + c;
      gload16(gaB + (size_t)(ch * 8) * DM + kt, (char*)As + ch * 1024);
    }
#pragma unroll
    for (int c = 0; c < 4; ++c) {
      const int ch = w * 4 + c;
      gload16(gbB + (size_t)(ch * 8) * DM + kt, (char*)Bs + ch * 1024);
    }
    __syncthreads();
#pragma unroll
    for (int kk = 0; kk < 2; ++kk) {
      bf16x8 a[ACH], b[4];
#pragma unroll
      for (int m = 0; m < ACH; ++m)
        a[m] = *(const bf16x8*)&As[(wr * (BM / 2) + m * 16 + cl) * 64 + kk * 32 + kg * 8];
#pragma unroll
      for (int n = 0; n < 4; ++n)
        b[n] = *(const bf16x8*)&Bs[(wc * 64 + n * 16 + cl) * 64 + kk * 32 + kg * 8];
#pragma unroll
      for (int m = 0; m < ACH; ++m)
#pragma unroll
        for (int n = 0; n < 4; ++n) {
          if (SWAP)
            acc[m][n] = __builtin_amdgcn_mfma_f32_16x16x32_bf16(b[n], a[m], acc[m][n], 0, 0, 0);
          else
            acc[m][n] = __builtin_amdgcn_mfma_f32_16x16x32_bf16(a[m], b[n], acc[m][n], 0, 0, 0);
        }
    }
  }
}

// Fused Q/K/V projections, 128x128 tiles, BK=64.  Grid: 1-D 768, XCD-chunked.
__global__ __launch_bounds__(256) void proj_gemm(
    const unsigned short* __restrict__ X0, const unsigned short* __restrict__ X1,
    const unsigned short* __restrict__ X2, const unsigned short* __restrict__ W0,
    const unsigned short* __restrict__ W1, const unsigned short* __restrict__ W2,
    const float* __restrict__ b0, const float* __restrict__ b1, const float* __restrict__ b2,
    unsigned short* __restrict__ Y0, unsigned short* __restrict__ Y1,
    unsigned short* __restrict__ Y2) {
  __shared__ unsigned short As[128 * 64];
  __shared__ unsigned short Bs[128 * 64];
  const int bid = blockIdx.x;
  const int wg = (bid & 7) * 96 + (bid >> 3);   // bijective: 768 = 8 * 96
  const int z = wg >> 8;
  const int rem = wg & 255;
  const int m0 = (rem >> 3) * 128, n0 = (rem & 7) * 128;

  const unsigned short* X = (z == 0) ? X0 : ((z == 1) ? X1 : X2);
  const unsigned short* W = (z == 0) ? W0 : ((z == 1) ? W1 : W2);
  const float* bias = (z == 0) ? b0 : ((z == 1) ? b1 : b2);

  const int l = threadIdx.x & 63, w = threadIdx.x >> 6;
  const int wr = w >> 1, wc = w & 1, cl = l & 15, kg = l >> 4;

  f32x4 acc[4][4] = {};
  if (z == 2) {
    gemm_core_bk64<128, 0>(X, W, As, Bs, m0, n0, acc);
#pragma unroll
    for (int i = 0; i < 4; ++i) {
#pragma unroll
      for (int j = 0; j < 4; ++j) {
        const int gn = n0 + wc * 64 + j * 16 + cl;
        const float bv = bias[gn];
        const int h_ = gn >> 6, d_ = gn & 63;
        const int gm0 = m0 + wr * 64 + i * 16 + kg * 4;
        const int b_ = gm0 >> 10, s0 = gm0 & 1023;
        u16x4 vv;
#pragma unroll
        for (int r = 0; r < 4; ++r) vv[r] = f2bf(acc[i][j][r] + bv);
        *(u16x4*)&Y2[((size_t)(b_ * NH + h_) * DH + d_) * S + s0] = vv;
      }
    }
  } else {
    gemm_core_bk64<128, 1>(X, W, As, Bs, m0, n0, acc);
    unsigned short* Y = (z == 0) ? Y0 : Y1;
    const bool scale = (z == 1);
#pragma unroll
    for (int i = 0; i < 4; ++i) {
      const int gm = m0 + wr * 64 + i * 16 + cl;
      const int b_ = gm >> 10, s_ = gm & 1023;
#pragma unroll
      for (int j = 0; j < 4; ++j) {
        const int gn0 = n0 + wc * 64 + j * 16 + kg * 4;
        const int h_ = gn0 >> 6, d0 = gn0 & 63;
        const f32x4 bv = *(const f32x4*)(bias + gn0);
        u16x4 vv;
#pragma unroll
        for (int r = 0; r < 4; ++r) {
          float val = acc[i][j][r] + bv[r];
          if (scale) val *= 0.125f;
          vv[r] = f2bf(val);
        }
        *(u16x4*)&Y[((size_t)(b_ * NH + h_) * S + s_) * DH + d0] = vv;
      }
    }
  }
}

// Final GEMM: out0 = OutH @ Wo^T + bo (fp32), 64x128 tiles, BK=64, SWAPPED.
__global__ __launch_bounds__(256) void out_gemm(const unsigned short* __restrict__ X,
                                                const unsigned short* __restrict__ W,
                                                const float* __restrict__ bias,
                                                float* __restrict__ Y) {
  __shared__ unsigned short As[64 * 64];
  __shared__ unsigned short Bs[128 * 64];
  const int bid = blockIdx.x;
  const int wg = (bid & 7) * 64 + (bid >> 3);   // 512 = 8 * 64
  const int m0 = (wg >> 3) * 64, n0 = (wg & 7) * 128;

  f32x4 acc[2][4] = {};
  gemm_core_bk64<64, 1>(X, W, As, Bs, m0, n0, acc);

  const int l = threadIdx.x & 63, w = threadIdx.x >> 6;
  const int wr = w >> 1, wc = w & 1, cl = l & 15, kg = l >> 4;
#pragma unroll
  for (int i = 0; i < 2; ++i) {
    const int gm = m0 + wr * 32 + i * 16 + cl;
#pragma unroll
    for (int j = 0; j < 4; ++j) {
      const int gn0 = n0 + wc * 64 + j * 16 + kg * 4;
      const f32x4 bv = *(const f32x4*)(bias + gn0);
      f32x4 st;
#pragma unroll
      for (int r = 0; r < 4; ++r) st[r] = acc[i][j][r] + bv[r];
      *(f32x4*)&Y[(size_t)gm * DM + gn0] = st;
    }
  }
}

// ---------------------------------------------------------------------------
// kv-split attention (R14-exact, best measured 194.2us): LDS-coalesced prob
// staging + NONTEMPORAL streaming stores (268MB bypasses L2 -> per-XCD K/V
// stay resident).  Block = 8 waves (512 thr), 32 q-rows; wave w owns kv
// [w*128, w*128+128).  Grid: 1-D 2048, XCD-chunked by head.
// ---------------------------------------------------------------------------
__global__ __launch_bounds__(512, 4) void attn_mfma(const unsigned short* __restrict__ Qh,
                                                    const unsigned short* __restrict__ Kh,
                                                    const unsigned short* __restrict__ Vt,
                                                    float* __restrict__ attn,
                                                    unsigned short* __restrict__ OutH) {
  __shared__ float sums[8][32];
  __shared__ float invs[32];
  __shared__ float Buf[8 * 32 * 66];            // 67.6 KB, dual-use
  unsigned short* Ppk = (unsigned short*)Buf;   // [32][1028] halfwords (65.8 KB)
  float (*Olds)[32][66] = (float (*)[32][66])Buf;

  const int t = threadIdx.x, l = t & 63, w = t >> 6;
  const int lq = l & 31, hi = l >> 5;
  const int bid = blockIdx.x;
  const int wg = (bid & 7) * 256 + (bid >> 3);  // bijective: 2048 = 8 * 256
  const int bh = wg >> 5;
  const int q0 = (wg & 31) * 32;

  const unsigned short* kb = Kh + (size_t)bh * S * DH;
  const unsigned short* vb = Vt + (size_t)bh * DH * S;

  unsigned e_pk[4][8];
  float sum = 0.f;

  // ---- pass A: QK^T + exp + partial row sums; retain packed exp(S) ----
  {
    const unsigned short* qp = Qh + ((size_t)bh * S + q0 + lq) * DH + hi * 8;
    bf16x8 qf0 = *(const bf16x8*)(qp);
    bf16x8 qf1 = *(const bf16x8*)(qp + 16);
    bf16x8 qf2 = *(const bf16x8*)(qp + 32);
    bf16x8 qf3 = *(const bf16x8*)(qp + 48);
#pragma unroll
    for (int kt = 0; kt < 4; ++kt) {
      const unsigned short* kp = kb + (size_t)(w * 128 + kt * 32 + lq) * DH + hi * 8;
      f32x16 acc = {};
      __builtin_amdgcn_s_setprio(1);
      acc = __builtin_amdgcn_mfma_f32_32x32x16_bf16(*(const bf16x8*)(kp),      qf0, acc, 0, 0, 0);
      acc = __builtin_amdgcn_mfma_f32_32x32x16_bf16(*(const bf16x8*)(kp + 16), qf1, acc, 0, 0, 0);
      acc = __builtin_amdgcn_mfma_f32_32x32x16_bf16(*(const bf16x8*)(kp + 32), qf2, acc, 0, 0, 0);
      acc = __builtin_amdgcn_mfma_f32_32x32x16_bf16(*(const bf16x8*)(kp + 48), qf3, acc, 0, 0, 0);
      __builtin_amdgcn_s_setprio(0);
      float e[16];
#pragma unroll
      for (int r = 0; r < 16; ++r) e[r] = __expf(acc[r]);
#pragma unroll
      for (int r = 0; r < 16; ++r) sum += e[r];
#pragma unroll
      for (int j = 0; j < 8; ++j) e_pk[kt][j] = cvt_pk_bf16(e[2 * j], e[2 * j + 1]);
    }
  }
  sum += __shfl_xor(sum, 32);
  if (l < 32) sums[w][lq] = sum;
  __syncthreads();
  float tot = 0.f;
#pragma unroll
  for (int p = 0; p < 8; ++p) tot += sums[p][lq];
  const float inv = 1.0f / tot;
  if (t < 32) invs[lq] = inv;   // wave 0, lanes 0..31

  // ---- pass B: P -> LDS (packed bf16) + PV on unnormalized e ----
  f32x16 o0 = {}, o1 = {};

#pragma unroll
  for (int kt = 0; kt < 4; ++kt) {
    // ds_write_b64: words (j, j+1) are kv-contiguous quads
#pragma unroll
    for (int j = 0; j < 8; j += 2) {
      const unsigned long long pv =
          ((unsigned long long)e_pk[kt][j + 1] << 32) | (unsigned long long)e_pk[kt][j];
      const int kvb = w * 128 + kt * 32 + (j >> 1) * 8 + 4 * hi;
      *(unsigned long long*)&Ppk[lq * 1028 + kvb] = pv;
    }

    // PV B-frags directly from the packed words (kv slices 0..15 / 16..31)
    const unsigned wds0 = e_pk[kt][0], wds1 = e_pk[kt][1];
    const unsigned wds2 = e_pk[kt][2], wds3 = e_pk[kt][3];
    const unsigned wds4 = e_pk[kt][4], wds5 = e_pk[kt][5];
    const unsigned wds6 = e_pk[kt][6], wds7 = e_pk[kt][7];
    const unsigned x0 = __shfl_xor((int)wds0, 32), x1 = __shfl_xor((int)wds1, 32);
    const unsigned x2 = __shfl_xor((int)wds2, 32), x3 = __shfl_xor((int)wds3, 32);
    const unsigned x4 = __shfl_xor((int)wds4, 32), x5 = __shfl_xor((int)wds5, 32);
    const unsigned x6 = __shfl_xor((int)wds6, 32), x7 = __shfl_xor((int)wds7, 32);
    union UU { unsigned u[4]; bf16x8 v; } f0, f1;
    f0.u[0] = hi ? x2 : wds0;  f0.u[1] = hi ? x3 : wds1;
    f0.u[2] = hi ? wds2 : x0;  f0.u[3] = hi ? wds3 : x1;
    f1.u[0] = hi ? x6 : wds4;  f1.u[1] = hi ? x7 : wds5;
    f1.u[2] = hi ? wds6 : x4;  f1.u[3] = hi ? wds7 : x5;

    {
      const unsigned short* vp = vb + (size_t)(lq)*S + w * 128 + kt * 32 + hi * 8;
      bf16x8 v0 = *(const bf16x8*)vp;
      bf16x8 v1 = *(const bf16x8*)(vp + 16);
      const unsigned short* vp1 = vb + (size_t)(32 + lq) * S + w * 128 + kt * 32 + hi * 8;
      bf16x8 v2 = *(const bf16x8*)vp1;
      bf16x8 v3 = *(const bf16x8*)(vp1 + 16);
      __builtin_amdgcn_s_setprio(1);
      o0 = __builtin_amdgcn_mfma_f32_32x32x16_bf16(v0, f0.v, o0, 0, 0, 0);
      o0 = __builtin_amdgcn_mfma_f32_32x32x16_bf16(v1, f1.v, o0, 0, 0, 0);
      o1 = __builtin_amdgcn_mfma_f32_32x32x16_bf16(v2, f0.v, o1, 0, 0, 0);
      o1 = __builtin_amdgcn_mfma_f32_32x32x16_bf16(v3, f1.v, o1, 0, 0, 0);
      __builtin_amdgcn_s_setprio(0);
    }
  }
  __syncthreads();  // all waves' P tiles in LDS

  // ---- streaming probs: coalesced 1KB-per-wave-store, NONTEMPORAL ----
  {
    float* ab = attn + ((size_t)bh << 20) + ((size_t)q0 << 10);
#pragma unroll
    for (int i = 0; i < 16; ++i) {
      const int f = t + i * 512;            // quad index 0..8191
      const int q = f >> 8, c4 = (f & 255) * 4;
      const unsigned long long pk = *(const unsigned long long*)&Ppk[q * 1028 + c4];
      const unsigned lo = (unsigned)pk, hi2 = (unsigned)(pk >> 32);
      const float iv = invs[q];
      f32x4 pv;
      pv[0] = __builtin_bit_cast(float, lo << 16) * iv;
      pv[1] = __builtin_bit_cast(float, lo & 0xffff0000u) * iv;
      pv[2] = __builtin_bit_cast(float, hi2 << 16) * iv;
      pv[3] = __builtin_bit_cast(float, hi2 & 0xffff0000u) * iv;
      __builtin_nontemporal_store(pv, (f32x4*)(ab + (size_t)q * 1024 + c4));
    }
  }
  __syncthreads();  // P region dead; Olds may overwrite

  // ---- apply row normalization once, combine partial O via LDS (f32x4) ----
#pragma unroll
  for (int r = 0; r < 16; ++r) { o0[r] *= inv; o1[r] *= inv; }
  {
    float* orow = &Olds[w][lq][0];
#pragma unroll
    for (int g = 0; g < 4; ++g) {
      f32x4 a = {o0[4 * g], o0[4 * g + 1], o0[4 * g + 2], o0[4 * g + 3]};
      *(f32x4*)(orow + 8 * g + 4 * hi) = a;           // d = 8g+4hi .. +3
      f32x4 b2 = {o1[4 * g], o1[4 * g + 1], o1[4 * g + 2], o1[4 * g + 3]};
      *(f32x4*)(orow + 32 + 8 * g + 4 * hi) = b2;     // d = 32+8g+4hi .. +3
    }
  }
  __syncthreads();

  {
    const int qq = t >> 4, d0 = (t & 15) * 4;   // all 512 threads
    const int b_ = bh >> 4, h_ = bh & 15;
    f32x4 s = {0.f, 0.f, 0.f, 0.f};
#pragma unroll
    for (int p = 0; p < 8; ++p) {
      const f32x4 v = *(const f32x4*)&Olds[p][qq][d0];
      s[0] += v[0]; s[1] += v[1]; s[2] += v[2]; s[3] += v[3];
    }
    u16x4 ov;
#pragma unroll
    for (int i = 0; i < 4; ++i) ov[i] = f2bf(s[i]);
    *(u16x4*)&OutH[((size_t)(b_ * S + q0 + qq)) * DM + h_ * DH + d0] = ov;
  }
}

// ---------------------------------------------------------------------------
extern "C" void kernel_launch(void* const* d_in, const int* in_sizes, int n_in,
                              void* d_out, int out_size, void* d_ws, size_t ws_size,
                              hipStream_t stream) {
  const float* query = (const float*)d_in[0];
  const float* key_  = (const float*)d_in[1];
  const float* value = (const float*)d_in[2];
  const float* Wq = (const float*)d_in[3];
  const float* bq = (const float*)d_in[4];
  const float* Wk = (const float*)d_in[5];
  const float* bk = (const float*)d_in[6];
  const float* Wv = (const float*)d_in[7];
  const float* bv = (const float*)d_in[8];
  const float* Wo = (const float*)d_in[9];
  const float* bo = (const float*)d_in[10];

  float* out0 = (float*)d_out;
  float* attn = out0 + (size_t)MTOK * DM;

  const size_t M1 = 1u << 20;
  unsigned short* wsu = (unsigned short*)d_ws;
  unsigned short* Xq  = wsu;
  unsigned short* Xk  = wsu + 4 * M1;
  unsigned short* Xv  = wsu + 8 * M1;
  unsigned short* Wqb = wsu + 12 * M1;
  unsigned short* Wkb = wsu + 13 * M1;
  unsigned short* Wvb = wsu + 14 * M1;
  unsigned short* Wob = wsu + 15 * M1;
  unsigned short* Qh  = wsu + 16 * M1;
  unsigned short* Kh  = wsu + 20 * M1;
  unsigned short* Vt  = wsu + 24 * M1;
  unsigned short* OutH= wsu + 28 * M1;

  dim3 tB(256);
  hipLaunchKernelGGL(cvt_all, dim3(2048), tB, 0, stream, query, key_, value, Wq, Wk, Wv, Wo,
                     Xq, Xk, Xv, Wqb, Wkb, Wvb, Wob);

  hipLaunchKernelGGL(proj_gemm, dim3(768), tB, 0, stream,
                     Xq, Xk, Xv, Wqb, Wkb, Wvb, bq, bk, bv, Qh, Kh, Vt);

  hipLaunchKernelGGL(attn_mfma, dim3(2048), dim3(512), 0, stream, Qh, Kh, Vt, attn, OutH);

  hipLaunchKernelGGL(out_gemm, dim3(512), tB, 0, stream, OutH, Wob, bo, out0);
}